// Round 1
// baseline (345.499 us; speedup 1.0000x reference)
//
#include <hip/hip_runtime.h>

// Differentiable histogram: img (128*512*512 f32) -> 256-bin linear-interp hist.
// HMIN=0, HMAX=1, NBIN=256, DH = 1/255 -> s = x*255, split weight (1-frac, frac)
// between bins idx and idx+1; bin 256 (overflow) is dropped.

#define NBIN   256
#define NB1    257      // bins + overflow slot for idx+1 == 256
#define BLOCK  256
#define WAVES  4        // BLOCK / 64
#define GRID   2048

__global__ __launch_bounds__(BLOCK) void diffhist_kernel(
    const float* __restrict__ img, float* __restrict__ out, long long n)
{
    // One private histogram per wave; stride 257 (odd) rotates bank mapping
    // between copies. 4 * 257 * 4B = 4112 B LDS.
    __shared__ float lh[WAVES * NB1];

    const int tid  = threadIdx.x;
    const int wave = tid >> 6;
    float* __restrict__ myh = &lh[wave * NB1];

    for (int i = tid; i < WAVES * NB1; i += BLOCK) lh[i] = 0.0f;
    __syncthreads();

    const long long gtid = (long long)blockIdx.x * BLOCK + tid;
    const long long gsz  = (long long)gridDim.x * BLOCK;
    const long long n4   = n >> 2;
    const float4* __restrict__ in4 = (const float4*)img;

    for (long long i = gtid; i < n4; i += gsz) {
        float4 v = in4[i];
        #pragma unroll
        for (int c = 0; c < 4; ++c) {
            float x = (c == 0) ? v.x : (c == 1) ? v.y : (c == 2) ? v.z : v.w;
            if (x >= 0.0f && x <= 1.0f) {
                float s = x * 255.0f;
                float f = floorf(s);
                float d = s - f;
                int   b = (int)f;
                atomicAdd(&myh[b],     1.0f - d);
                atomicAdd(&myh[b + 1], d);
            }
        }
    }

    // scalar tail (n is divisible by 4 here, but stay general)
    for (long long i = (n4 << 2) + gtid; i < n; i += gsz) {
        float x = img[i];
        if (x >= 0.0f && x <= 1.0f) {
            float s = x * 255.0f;
            float f = floorf(s);
            float d = s - f;
            int   b = (int)f;
            atomicAdd(&myh[b],     1.0f - d);
            atomicAdd(&myh[b + 1], d);
        }
    }

    __syncthreads();

    // Reduce the per-wave copies; one global atomic per bin per block.
    for (int b = tid; b < NBIN; b += BLOCK) {
        float s = lh[b] + lh[NB1 + b] + lh[2 * NB1 + b] + lh[3 * NB1 + b];
        atomicAdd(&out[b], s);
    }
}

extern "C" void kernel_launch(void* const* d_in, const int* in_sizes, int n_in,
                              void* d_out, int out_size, void* d_ws, size_t ws_size,
                              hipStream_t stream) {
    const float* img = (const float*)d_in[0];
    float* out = (float*)d_out;
    const long long n = (long long)in_sizes[0];

    // Harness poisons d_out once and never re-zeroes between replays;
    // zero it ourselves every call (stream memset is graph-capture safe).
    hipMemsetAsync(d_out, 0, (size_t)out_size * sizeof(float), stream);

    diffhist_kernel<<<GRID, BLOCK, 0, stream>>>(img, out, n);
}

// Round 2
// 344.033 us; speedup vs baseline: 1.0043x; 1.0043x over previous
//
#include <hip/hip_runtime.h>

// Differentiable histogram: img (128*512*512 f32) -> 256-bin linear-interp hist.
// s = x*255; split (1-frac, frac) between bins b and b+1; bin 256 dropped.
//
// R2 design:
//  - 32 LDS histogram copies in TRANSPOSED layout lh[bin][copy], lane uses
//    copy = lane&31  => LDS bank = lane&31 always => ds_add_f32 is
//    conflict-free by construction (2 lanes/bank from wave64 = free).
//  - No global atomics: per-block partials to d_ws ([bin][block]), second
//    kernel tree-reduces coalesced and writes out[bin] directly.

#define NBIN   256
#define NB1    257      // + overflow slot for b+1 == 256
#define NCOPY  32
#define BLK1   512
#define GRID1  1024
#define BLK2   256

__global__ __launch_bounds__(BLK1) void diffhist_partial(
    const float* __restrict__ img, float* __restrict__ partial, long long n)
{
    // 257 bins x 32 copies, transposed: element (bin,c) at lh[bin*32 + c].
    // Bank of (bin*32 + c) is c -> lane-exclusive banks.
    __shared__ float lh[NB1 * NCOPY];   // 32,896 B

    const int tid = threadIdx.x;
    const int c   = tid & 31;

    for (int i = tid; i < NB1 * NCOPY; i += BLK1) lh[i] = 0.0f;
    __syncthreads();

    const long long gtid = (long long)blockIdx.x * BLK1 + tid;
    const long long gsz  = (long long)gridDim.x * BLK1;
    const long long n4   = n >> 2;
    const float4* __restrict__ in4 = (const float4*)img;

    for (long long i = gtid; i < n4; i += gsz) {
        float4 v = in4[i];
        #pragma unroll
        for (int k = 0; k < 4; ++k) {
            float x = (k == 0) ? v.x : (k == 1) ? v.y : (k == 2) ? v.z : v.w;
            if (x >= 0.0f && x <= 1.0f) {
                float s = x * 255.0f;
                float f = floorf(s);
                float d = s - f;
                int   b = (int)f;
                atomicAdd(&lh[b * NCOPY + c],       1.0f - d);
                atomicAdd(&lh[(b + 1) * NCOPY + c], d);
            }
        }
    }
    // tail (n divisible by 4 in practice)
    for (long long i = (n4 << 2) + gtid; i < n; i += gsz) {
        float x = img[i];
        if (x >= 0.0f && x <= 1.0f) {
            float s = x * 255.0f;
            float f = floorf(s);
            float d = s - f;
            int   b = (int)f;
            atomicAdd(&lh[b * NCOPY + c],       1.0f - d);
            atomicAdd(&lh[(b + 1) * NCOPY + c], d);
        }
    }

    __syncthreads();

    // Reduce 32 copies per bin; rotated copy index keeps banks conflict-free.
    if (tid < NBIN) {
        float s = 0.0f;
        #pragma unroll
        for (int k = 0; k < NCOPY; ++k) {
            s += lh[tid * NCOPY + ((tid + k) & 31)];
        }
        partial[(long long)tid * gridDim.x + blockIdx.x] = s;
    }
}

__global__ __launch_bounds__(BLK2) void diffhist_reduce(
    const float* __restrict__ partial, float* __restrict__ out, int G)
{
    const int b = blockIdx.x;                 // bin
    const float* __restrict__ p = partial + (long long)b * G;

    float s = 0.0f;
    for (int i = threadIdx.x; i < G; i += BLK2) s += p[i];

    #pragma unroll
    for (int off = 32; off > 0; off >>= 1) s += __shfl_down(s, off, 64);

    __shared__ float wsum[BLK2 / 64];
    const int wave = threadIdx.x >> 6;
    const int lane = threadIdx.x & 63;
    if (lane == 0) wsum[wave] = s;
    __syncthreads();
    if (threadIdx.x == 0) {
        float tot = 0.0f;
        #pragma unroll
        for (int w = 0; w < BLK2 / 64; ++w) tot += wsum[w];
        out[b] = tot;
    }
}

extern "C" void kernel_launch(void* const* d_in, const int* in_sizes, int n_in,
                              void* d_out, int out_size, void* d_ws, size_t ws_size,
                              hipStream_t stream) {
    const float* img = (const float*)d_in[0];
    float* out = (float*)d_out;
    float* partial = (float*)d_ws;
    const long long n = (long long)in_sizes[0];

    // Need GRID1*NBIN*4 bytes of scratch; clamp grid if ws is smaller.
    int G = GRID1;
    size_t need = (size_t)G * NBIN * sizeof(float);
    if (ws_size < need) {
        G = (int)(ws_size / ((size_t)NBIN * sizeof(float)));
        if (G < 1) G = 1;
    }

    diffhist_partial<<<G, BLK1, 0, stream>>>(img, partial, n);
    // d_out fully overwritten by reduce kernel (no memset needed).
    diffhist_reduce<<<NBIN, BLK2, 0, stream>>>(partial, out, G);
}

// Round 3
// 30.852 us; speedup vs baseline: 11.1987x; 11.1512x over previous
//
#include <hip/hip_runtime.h>

// Differentiable histogram: img (128*512*512 f32) -> 256-bin linear-interp hist.
// s = x*255; split (1-frac, frac) between bins b and b+1; bin 256 dropped.
//
// R3 design:
//  - fp32 LDS atomicAdd was the bottleneck (CAS-loop lowering, ~200 cy/atomic,
//    all pipes idle). Replace with NATIVE integer atomics: 16.16 fixed-point
//    weights, ds_add_u32. w0+w1 == 65536 exactly -> total mass exact;
//    per-bin quantization error ~1.0 vs threshold 2642.
//  - 32 LDS copies, transposed layout lh[bin*32 + (lane&31)]: bank = lane&31,
//    conflict-free by construction.
//  - Max per-counter sum: (32768 elem/block / 32 copies * upTo4 lanes share)
//    = 4096 elem * 2^16 = 2^28 << 2^32. No overflow.
//  - No global atomics: per-block fp32 partials to d_ws ([bin][block]),
//    second kernel reduces coalesced and writes out[bin].

#define NBIN   256
#define NB1    257      // + overflow slot for b+1 == 256
#define NCOPY  32
#define BLK1   512
#define GRID1  1024
#define BLK2   256

__global__ __launch_bounds__(BLK1) void diffhist_partial(
    const float* __restrict__ img, float* __restrict__ partial, long long n)
{
    // 257 bins x 32 copies, transposed: element (bin,c) at lh[bin*32 + c].
    __shared__ unsigned lh[NB1 * NCOPY];   // 32,896 B

    const int tid = threadIdx.x;
    const int c   = tid & 31;

    for (int i = tid; i < NB1 * NCOPY; i += BLK1) lh[i] = 0u;
    __syncthreads();

    const long long gtid = (long long)blockIdx.x * BLK1 + tid;
    const long long gsz  = (long long)gridDim.x * BLK1;
    const long long n4   = n >> 2;
    const float4* __restrict__ in4 = (const float4*)img;

    for (long long i = gtid; i < n4; i += gsz) {
        float4 v = in4[i];
        #pragma unroll
        for (int k = 0; k < 4; ++k) {
            float x = (k == 0) ? v.x : (k == 1) ? v.y : (k == 2) ? v.z : v.w;
            if (x >= 0.0f && x <= 1.0f) {
                float s = x * 255.0f;
                float f = floorf(s);
                float d = s - f;
                int   b = (int)f;
                unsigned w1 = (unsigned)(d * 65536.0f + 0.5f);  // [0, 65536]
                unsigned w0 = 65536u - w1;
                atomicAdd(&lh[b * NCOPY + c],       w0);   // native ds_add_u32
                atomicAdd(&lh[(b + 1) * NCOPY + c], w1);
            }
        }
    }
    // tail (n divisible by 4 in practice)
    for (long long i = (n4 << 2) + gtid; i < n; i += gsz) {
        float x = img[i];
        if (x >= 0.0f && x <= 1.0f) {
            float s = x * 255.0f;
            float f = floorf(s);
            float d = s - f;
            int   b = (int)f;
            unsigned w1 = (unsigned)(d * 65536.0f + 0.5f);
            unsigned w0 = 65536u - w1;
            atomicAdd(&lh[b * NCOPY + c],       w0);
            atomicAdd(&lh[(b + 1) * NCOPY + c], w1);
        }
    }

    __syncthreads();

    // Reduce 32 copies per bin (u64 accumulate, exact), emit fp32 partial.
    if (tid < NBIN) {
        unsigned long long s = 0ull;
        #pragma unroll
        for (int k = 0; k < NCOPY; ++k) {
            s += (unsigned long long)lh[tid * NCOPY + ((tid + k) & 31)];
        }
        partial[(long long)tid * gridDim.x + blockIdx.x] =
            (float)((double)s * (1.0 / 65536.0));
    }
}

__global__ __launch_bounds__(BLK2) void diffhist_reduce(
    const float* __restrict__ partial, float* __restrict__ out, int G)
{
    const int b = blockIdx.x;                 // bin
    const float* __restrict__ p = partial + (long long)b * G;

    float s = 0.0f;
    for (int i = threadIdx.x; i < G; i += BLK2) s += p[i];

    #pragma unroll
    for (int off = 32; off > 0; off >>= 1) s += __shfl_down(s, off, 64);

    __shared__ float wsum[BLK2 / 64];
    const int wave = threadIdx.x >> 6;
    const int lane = threadIdx.x & 63;
    if (lane == 0) wsum[wave] = s;
    __syncthreads();
    if (threadIdx.x == 0) {
        float tot = 0.0f;
        #pragma unroll
        for (int w = 0; w < BLK2 / 64; ++w) tot += wsum[w];
        out[b] = tot;
    }
}

extern "C" void kernel_launch(void* const* d_in, const int* in_sizes, int n_in,
                              void* d_out, int out_size, void* d_ws, size_t ws_size,
                              hipStream_t stream) {
    const float* img = (const float*)d_in[0];
    float* out = (float*)d_out;
    float* partial = (float*)d_ws;
    const long long n = (long long)in_sizes[0];

    int G = GRID1;
    size_t need = (size_t)G * NBIN * sizeof(float);
    if (ws_size < need) {
        G = (int)(ws_size / ((size_t)NBIN * sizeof(float)));
        if (G < 1) G = 1;
    }

    diffhist_partial<<<G, BLK1, 0, stream>>>(img, partial, n);
    // d_out fully overwritten by reduce kernel (no memset needed).
    diffhist_reduce<<<NBIN, BLK2, 0, stream>>>(partial, out, G);
}